// Round 4
// baseline (401.366 us; speedup 1.0000x reference)
//
#include <hip/hip_runtime.h>
#include <cstdint>
#include <cstddef>

#define HH 300
#define WW 400
#define HWPIX (HH*WW)

typedef __attribute__((ext_vector_type(8))) short short8_t;
typedef __attribute__((ext_vector_type(4))) float f32x4;

static __device__ __forceinline__ unsigned short f2bf(float f){
  union { float f; unsigned u; } v; v.f = f;
  unsigned r = (v.u + 0x7fffu + ((v.u >> 16) & 1u)) >> 16;
  return (unsigned short)r;
}
static __device__ __forceinline__ float bf2f(unsigned short us){
  union { unsigned u; float f; } v; v.u = ((unsigned)us) << 16;
  return v.f;
}
// True per-op-rounded dots: pragma blocks FMA contraction at IR level
// (NOTE: __fmul_rn/__fadd_rn in ROCm are plain *,+ and DO get contracted).
static __device__ __forceinline__ float dot4_x(float a0,float x0,float a1,float x1,
                                               float a2,float x2,float a3,float x3){
  #pragma clang fp contract(off)
  float s = a0*x0;
  s = s + a1*x1;
  s = s + a2*x2;
  s = s + a3*x3;
  return s;
}
static __device__ __forceinline__ float dot3_x(float a0,float x0,float a1,float x1,
                                               float a2,float x2){
  #pragma clang fp contract(off)
  float s = a0*x0;
  s = s + a1*x1;
  s = s + a2*x2;
  return s;
}

// ---------------------------------------------------------------------------
// prep: blocks 0..255 transpose+convert W1[0:256] -> W1aT (bf16, [n][k]);
// block 256 packs ntab[n][8] = {W1 rows 256..258 (vdir), W2 cols 0..2, pad}
// and inverts poses.
// ---------------------------------------------------------------------------
__global__ void prep_kernel(const float* __restrict__ W1, const float* __restrict__ W2,
                            const float* __restrict__ pose,
                            float* __restrict__ poseinv, unsigned short* __restrict__ W1aT,
                            float* __restrict__ ntab, int B){
  int tid = threadIdx.x;
  int bid = blockIdx.x;
  if (bid < 256){
    int k = bid, n = tid;
    W1aT[n*256 + k] = f2bf(W1[k*256 + n]);
  } else {
    int n = tid;
    ntab[n*8+0] = W1[256*256 + n];
    ntab[n*8+1] = W1[257*256 + n];
    ntab[n*8+2] = W1[258*256 + n];
    ntab[n*8+3] = W2[n*3+0];
    ntab[n*8+4] = W2[n*3+1];
    ntab[n*8+5] = W2[n*3+2];
    ntab[n*8+6] = 0.f; ntab[n*8+7] = 0.f;
    if (tid < B){
      float M[4][8];
      const float* A = pose + tid*16;
      for (int i=0;i<4;i++) for (int j=0;j<4;j++){ M[i][j]=A[i*4+j]; M[i][4+j] = (i==j)?1.f:0.f; }
      for (int c=0;c<4;c++){
        int p=c;
        for (int r=c+1;r<4;r++) if (fabsf(M[r][c])>fabsf(M[p][c])) p=r;
        if (p!=c) for (int j=0;j<8;j++){ float t=M[c][j]; M[c][j]=M[p][j]; M[p][j]=t; }
        float inv = 1.f/M[c][c];
        for (int j=0;j<8;j++) M[c][j]*=inv;
        for (int r=0;r<4;r++) if (r!=c){ float f=M[r][c]; for(int j=0;j<8;j++) M[r][j]-=f*M[c][j]; }
      }
      float* O = poseinv + tid*16;
      for (int i=0;i<4;i++) for (int j=0;j<4;j++) O[i*4+j]=M[i][4+j];
    }
  }
}

// ---------------------------------------------------------------------------
// Fused: bf16 MFMA GEMM (64 verts x 256 hid, K=256) -> +b1 -> LDS(bf16) ->
// per-batch vdir correction + relu + layer2 + sigmoid -> atomic scatter.
// Projection uses contract(off) per-op fp32 in numpy order so pixel binning
// (rintf at .5 boundaries) bit-matches the numpy f32 reference.
// ---------------------------------------------------------------------------
__global__ __launch_bounds__(256) void mlp_scatter_kernel(
    const float* __restrict__ feat, const unsigned short* __restrict__ W1aT,
    const float* __restrict__ b1, const float* __restrict__ b2,
    const float* __restrict__ ntab,
    const float* __restrict__ vp, const float* __restrict__ opy,
    const float* __restrict__ pose, const float* __restrict__ intr,
    const float* __restrict__ poseinv,
    float* __restrict__ num, float* __restrict__ den, int N, int B)
{
  __shared__ __align__(16) char smem[40960];
  unsigned short* sA = (unsigned short*)smem;            // 64*64*2  = 8192 B
  unsigned short* sB = (unsigned short*)(smem + 8192);   // 256*64*2 = 32768 B
  unsigned short* sH = (unsigned short*)smem;            // phase2: 64*270*2 = 34560 B
  float* part        = (float*)(smem + 34560);           // 256*3*4 = 3072 B

  const int tid  = threadIdx.x;
  const int lane = tid & 63;
  const int wv   = __builtin_amdgcn_readfirstlane(tid >> 6);
  const int lr   = lane & 15;
  const int qd   = lane >> 4;
  const int m0   = blockIdx.x * 64;

  f32x4 acc[4][4];
  for (int i=0;i<4;i++) for (int j=0;j<4;j++) acc[i][j] = (f32x4){0.f,0.f,0.f,0.f};

  for (int kt=0; kt<4; kt++){
    #pragma unroll
    for (int i=0;i<4;i++){
      int q   = i*256 + tid;
      int row = q >> 4;
      int c4  = q & 15;
      long rg = m0 + row; if (rg >= N) rg = N-1;
      float4 f = *(const float4*)(feat + rg*256 + kt*64 + c4*4);
      ushort4 u;
      u.x = f2bf(f.x); u.y = f2bf(f.y); u.z = f2bf(f.z); u.w = f2bf(f.w);
      int q8 = c4 >> 1, half = c4 & 1;
      int phys = q8 ^ (row & 7);
      *(ushort4*)(sA + row*64 + phys*8 + half*4) = u;
    }
    #pragma unroll
    for (int i=0;i<8;i++){
      int q  = i*256 + tid;
      int n  = q >> 3;
      int c8 = q & 7;
      uint4 v = *(const uint4*)(W1aT + n*256 + kt*64 + c8*8);
      int phys = c8 ^ (n & 7);
      *(uint4*)(sB + n*64 + phys*8) = v;
    }
    __syncthreads();
    #pragma unroll
    for (int ks=0; ks<2; ks++){
      short8_t av[4], bv[4];
      int qlog = ks*4 + qd;
      #pragma unroll
      for (int mt=0; mt<4; mt++){
        int row  = mt*16 + lr;
        int phys = qlog ^ (row & 7);
        av[mt] = *(const short8_t*)(sA + row*64 + phys*8);
      }
      #pragma unroll
      for (int nt=0; nt<4; nt++){
        int n    = wv*64 + nt*16 + lr;
        int phys = qlog ^ (n & 7);
        bv[nt] = *(const short8_t*)(sB + n*64 + phys*8);
      }
      #pragma unroll
      for (int mt=0; mt<4; mt++)
        #pragma unroll
        for (int nt=0; nt<4; nt++)
          acc[mt][nt] = __builtin_amdgcn_mfma_f32_16x16x32_bf16(av[mt], bv[nt], acc[mt][nt], 0,0,0);
    }
    __syncthreads();
  }

  #pragma unroll
  for (int nt=0; nt<4; nt++){
    int n = wv*64 + nt*16 + lr;
    float bias = b1[n];
    #pragma unroll
    for (int mt=0; mt<4; mt++)
      #pragma unroll
      for (int rr=0; rr<4; rr++){
        int m = mt*16 + qd*4 + rr;   // C/D: row = quad*4+reg, col = lane&15
        sH[m*270 + n] = f2bf(acc[mt][nt][rr] + bias);
      }
  }
  __syncthreads();

  // ---- phase 2 ----
  const int r = lane;
  long vg = m0 + r;
  bool rowok = vg < N; if (!rowok) vg = N-1;
  float px = vp[vg], py = vp[(size_t)N+vg], pz = vp[2*(size_t)N+vg];
  const float* tb = ntab + (size_t)wv*64*8;
  const unsigned short* hrow = sH + r*270 + wv*64;

  for (int b=0; b<B; b++){
    const float* P  = pose + b*16;
    const float* Kc = intr + b*9;
    const float* Pi = poseinv + b*16;
    // per-op rounded, in numpy order, contraction OFF
    float xt = dot4_x(P[0],px, P[1],py, P[2], pz, P[3], 1.f);
    float yt = dot4_x(P[4],px, P[5],py, P[6], pz, P[7], 1.f);
    float zt = dot4_x(P[8],px, P[9],py, P[10],pz, P[11],1.f);
    float uu = dot3_x(Kc[0],xt, Kc[1],yt, Kc[2],zt);
    float vv = dot3_x(Kc[3],xt, Kc[4],yt, Kc[5],zt);
    float zp = dot3_x(Kc[6],xt, Kc[7],yt, Kc[8],zt);
    bool em = fabsf(zp) < 0.01f;
    float zsafe = em ? 0.01f : zp;
    float up   = em ? -1e6f : uu/zsafe;   // IEEE correctly-rounded divide
    float vpix = em ? -1e6f : vv/zsafe;
    float zz   = em ? -1e6f : zsafe;
    float inrm = 1.f/sqrtf(xt*xt + yt*yt + zt*zt);
    float nx=xt*inrm, ny=yt*inrm, nz=zt*inrm;
    float vdx = Pi[0]*nx + Pi[1]*ny + Pi[2]*nz;
    float vdy = Pi[4]*nx + Pi[5]*ny + Pi[6]*nz;
    float vdz = Pi[8]*nx + Pi[9]*ny + Pi[10]*nz;

    float a0=0.f, a1=0.f, a2=0.f;
    #pragma unroll 8
    for (int j=0;j<64;j++){
      const float* t = tb + j*8;
      float h = bf2f(hrow[j]) + vdx*t[0] + vdy*t[1] + vdz*t[2];
      h = fmaxf(h, 0.f);
      a0 += h*t[3]; a1 += h*t[4]; a2 += h*t[5];
    }
    part[(wv*64 + r)*3 + 0] = a0;
    part[(wv*64 + r)*3 + 1] = a1;
    part[(wv*64 + r)*3 + 2] = a2;
    __syncthreads();
    if (wv == 0){
      float s0 = part[r*3+0] + part[(64+r)*3+0] + part[(128+r)*3+0] + part[(192+r)*3+0];
      float s1 = part[r*3+1] + part[(64+r)*3+1] + part[(128+r)*3+1] + part[(192+r)*3+1];
      float s2 = part[r*3+2] + part[(64+r)*3+2] + part[(128+r)*3+2] + part[(192+r)*3+2];
      float r0 = 1.f/(1.f+expf(-(s0 + b2[0])));
      float r1 = 1.f/(1.f+expf(-(s1 + b2[1])));
      float r2 = 1.f/(1.f+expf(-(s2 + b2[2])));
      float opac = 1.f/(1.f+expf(-opy[vg]));  // clip(sigmoid,0,1) is a no-op
      int ix = (int)rintf(up);                 // round-half-even == np.round
      int iy = (int)rintf(vpix);
      bool valid = rowok && ix>=0 && ix<WW && iy>=0 && iy<HH && zz>=1.0f;
      if (valid){
        int idx = iy*WW + ix;
        atomicAdd(den + (size_t)b*HWPIX + idx, opac);
        atomicAdd(num + ((size_t)b*3+0)*HWPIX + idx, opac*r0);
        atomicAdd(num + ((size_t)b*3+1)*HWPIX + idx, opac*r1);
        atomicAdd(num + ((size_t)b*3+2)*HWPIX + idx, opac*r2);
      }
    }
    __syncthreads();
  }
}

// ---------------------------------------------------------------------------
// In-place: d_out currently holds num (B,3,HW); convert to final image.
__global__ void compose_kernel(float* __restrict__ out, const float* __restrict__ den,
                               const float* __restrict__ bkg, int B){
  int i = blockIdx.x*256 + threadIdx.x;
  int total = B*HWPIX;
  if (i >= total) return;
  int b = i / HWPIX;
  int pix = i - b*HWPIX;
  float d = den[i];
  float alpha = 1.f - expf(-d);
  float om = 1.f - alpha;
  float dd = d + 1e-8f;
  float* ob = out + (size_t)b*3*HWPIX;
  float f0 = ob[0*HWPIX + pix] / dd;
  float f1 = ob[1*HWPIX + pix] / dd;
  float f2 = ob[2*HWPIX + pix] / dd;
  ob[0*HWPIX + pix] = f0*alpha + bkg[0]*om;
  ob[1*HWPIX + pix] = f1*alpha + bkg[1]*om;
  ob[2*HWPIX + pix] = f2*alpha + bkg[2]*om;
}

// ---------------------------------------------------------------------------
extern "C" void kernel_launch(void* const* d_in, const int* in_sizes, int n_in,
                              void* d_out, int out_size, void* d_ws, size_t ws_size,
                              hipStream_t stream){
  const float* vp   = (const float*)d_in[0];
  // d_in[1] = ref_images: unused by the reference computation
  const float* pose = (const float*)d_in[2];
  const float* intr = (const float*)d_in[3];
  const float* feat = (const float*)d_in[4];
  const float* opy  = (const float*)d_in[5];
  const float* W1   = (const float*)d_in[6];
  const float* b1   = (const float*)d_in[7];
  const float* W2   = (const float*)d_in[8];
  const float* b2   = (const float*)d_in[9];
  const float* bkg  = (const float*)d_in[10];
  float* out = (float*)d_out;
  int N = in_sizes[0]/3;
  int B = in_sizes[2]/16;

  char* ws = (char*)d_ws;
  float* poseinv        = (float*)ws;                          // 256 B
  unsigned short* W1aT  = (unsigned short*)(ws + 256);         // 131072 B
  float* ntab           = (float*)(ws + 256 + 131072);         // 8192 B
  float* den            = (float*)(ws + 256 + 131072 + 8192);  // B*HWPIX floats

  hipMemsetAsync(out, 0, (size_t)out_size*sizeof(float), stream);
  hipMemsetAsync(den, 0, (size_t)B*HWPIX*sizeof(float), stream);
  prep_kernel<<<257, 256, 0, stream>>>(W1, W2, pose, poseinv, W1aT, ntab, B);
  int gridM = (N + 63)/64;
  mlp_scatter_kernel<<<gridM, 256, 0, stream>>>(feat, W1aT, b1, b2, ntab, vp, opy,
                                                pose, intr, poseinv, out, den, N, B);
  compose_kernel<<<(B*HWPIX + 255)/256, 256, 0, stream>>>(out, den, bkg, B);
}